// Round 11
// baseline (470.907 us; speedup 1.0000x reference)
//
#include <hip/hip_runtime.h>
#include <hip/hip_bf16.h>
#include <hip/hip_fp16.h>

typedef __attribute__((ext_vector_type(8))) short short8;
typedef __attribute__((ext_vector_type(4))) short short4v;
typedef __attribute__((ext_vector_type(8))) _Float16 f16x8;
typedef __attribute__((ext_vector_type(4))) _Float16 f16x4;
typedef __attribute__((ext_vector_type(4))) float f32x4;

static constexpr int BATCH   = 256;
static constexpr int NIN     = 128;
static constexpr int NH1     = 512;
static constexpr int NH2     = 256;
static constexpr int TC      = 250;   // chunk length (2 chunks of 250)
static constexpr int NCHUNK  = 2;
static constexpr float LO_SCALE = 4096.0f;        // 2^12
static constexpr float LO_INV   = 2.44140625e-4f; // 2^-12

__device__ __forceinline__ unsigned short f2h_bits(float x) {
    _Float16 h = (_Float16)x;
    unsigned short u;
    __builtin_memcpy(&u, &h, 2);
    return u;
}
__device__ __forceinline__ float h2f(unsigned short u) {
    _Float16 h;
    __builtin_memcpy(&h, &u, 2);
    return (float)h;
}

// Split f32 weights into 2 f16 components: w = hi + lo*2^-12 (residual ~|w|*2^-23).
// Also zeroes the two atomic spike counters (deterministic each launch).
__global__ __launch_bounds__(256) void prep_weights(
    const float* __restrict__ W1, const float* __restrict__ W2,
    unsigned short* __restrict__ w1s,   // [2][512*128] f16 bits
    unsigned short* __restrict__ w2s,   // [2][256*512]
    unsigned int* __restrict__ cnt1, unsigned int* __restrict__ cnt2)
{
    int idx = blockIdx.x * 256 + threadIdx.x;
    if (idx == 0) { cnt1[0] = 0u; cnt2[0] = 0u; }
    const int n1 = NH1 * NIN;   // 65536
    const int n2 = NH2 * NH1;   // 131072
    if (idx < n1) {
        float w = W1[idx];
        unsigned short hi = f2h_bits(w);
        float r = (w - h2f(hi)) * LO_SCALE;
        unsigned short lo = f2h_bits(r);
        w1s[idx] = hi; w1s[n1 + idx] = lo;
    }
    if (idx < n2) {
        float w = W2[idx];
        unsigned short hi = f2h_bits(w);
        float r = (w - h2f(hi)) * LO_SCALE;
        unsigned short lo = f2h_bits(r);
        w2s[idx] = hi; w2s[n2 + idx] = lo;
    }
}

// Pack f32 spikes (exact 0/1) into bits, element order preserved.
__global__ __launch_bounds__(256) void pack_spikes(
    const float* __restrict__ sp, unsigned long long* __restrict__ bits)
{
    int i = blockIdx.x * 256 + threadIdx.x;   // 16,384,000 threads
    bool b = sp[i] != 0.0f;
    unsigned long long m = __ballot(b);
    if ((threadIdx.x & 63) == 0) bits[i >> 6] = m;
}

// Unified bit-A GEMM, BARRIER-FREE K-loop:
// C[M,N] = bits(A)[M,K] * (Bhi + 2^-12*Blo)[N,K]^T + bias
// BM=128 BN=128; 4 waves 2x2, wave tile 64x64 (4x4 of 16x16), dual f32 acc.
// B: fragments are contiguous 16B/lane -> load DIRECTLY from L2 into registers
//    (panels are 256-512KB, L2-resident; no LDS staging, no __syncthreads in
//    the K-loop). Double-buffered in named register sets (static indexing).
// A: bit-packed; conflict-free nibble LUT (16 x 8B = 1:1 banks; broadcast).
template<int N, int K>
__global__ __launch_bounds__(256) void gemm_bits(
    const unsigned char* __restrict__ Ab,    // [M][K/8]
    const unsigned short* __restrict__ Bs,   // [2][N*K] f16 bits
    const float* __restrict__ bias,
    float* __restrict__ C,
    int M)
{
    constexpr int NK = N * K;
    constexpr int nk = K / 32;               // K-steps (BK=32), even
    constexpr int kb = K / 8;

    __shared__ __align__(16) unsigned short lut4[64];   // 16 x 4 f16 = 128 B

    const int tid  = threadIdx.x;
    const int w    = tid >> 6;
    const int lane = tid & 63;
    const int lr   = lane & 15;
    const int lk   = lane >> 4;
    const int wr   = w >> 1;
    const int wc   = w & 1;

    if (tid < 16) {
        short4v e;
#pragma unroll
        for (int i = 0; i < 4; ++i)
            e[i] = ((tid >> i) & 1) ? (short)0x3C00 : (short)0;
        *reinterpret_cast<short4v*>(&lut4[tid * 4]) = e;
    }
    __syncthreads();   // LUT ready; no further barriers

    const int m0 = blockIdx.x * 128;
    const int n0 = blockIdx.y * 128;

    // A byte pointers (4 fragment rows)
    const unsigned char* aptr[4];
#pragma unroll
    for (int rb = 0; rb < 4; ++rb)
        aptr[rb] = Ab + (size_t)(m0 + wr * 64 + rb * 16 + lr) * kb + lk;

    // B fragment base: row n0+wc*64+lr, k-chunk lk*8; frag(cb,s) at
    // base + cb*16*K + s*NK (compile-time strides)
    const unsigned short* bptr = Bs + (size_t)(n0 + wc * 64 + lr) * K + lk * 8;

    f32x4 accH[4][4], accL[4][4];
#pragma unroll
    for (int i = 0; i < 4; ++i)
#pragma unroll
        for (int j = 0; j < 4; ++j) {
            accH[i][j] = (f32x4){0.f, 0.f, 0.f, 0.f};
            accL[i][j] = (f32x4){0.f, 0.f, 0.f, 0.f};
        }

    // double-buffered register sets (named -> static indexing, rule #20)
    f16x8 b0H[4], b0L[4], b1H[4], b1L[4];
    unsigned int a0[4], a1[4];

    // prologue: load step 0 into set0
#pragma unroll
    for (int cb = 0; cb < 4; ++cb) {
        b0H[cb] = *reinterpret_cast<const f16x8*>(bptr + cb * 16 * K);
        b0L[cb] = *reinterpret_cast<const f16x8*>(bptr + NK + cb * 16 * K);
    }
#pragma unroll
    for (int rb = 0; rb < 4; ++rb) a0[rb] = *aptr[rb];

#pragma unroll
    for (int ks = 0; ks < nk; ks += 2) {
        // load step ks+1 into set1 (always exists: nk even, ks < nk)
        {
            const int k1 = (ks + 1) * 32;
#pragma unroll
            for (int cb = 0; cb < 4; ++cb) {
                b1H[cb] = *reinterpret_cast<const f16x8*>(bptr + cb * 16 * K + k1);
                b1L[cb] = *reinterpret_cast<const f16x8*>(bptr + NK + cb * 16 * K + k1);
            }
#pragma unroll
            for (int rb = 0; rb < 4; ++rb) a1[rb] = aptr[rb][(ks + 1) * 4];
        }
        // compute step ks from set0
        {
            f16x8 af[4];
#pragma unroll
            for (int rb = 0; rb < 4; ++rb) {
                unsigned int b = a0[rb];
                f16x4 lo = *reinterpret_cast<const f16x4*>(&lut4[(b & 15u) * 4]);
                f16x4 hi = *reinterpret_cast<const f16x4*>(&lut4[((b >> 4) & 15u) * 4]);
                af[rb] = __builtin_shufflevector(lo, hi, 0, 1, 2, 3, 4, 5, 6, 7);
            }
#pragma unroll
            for (int cb = 0; cb < 4; ++cb)
#pragma unroll
                for (int rb = 0; rb < 4; ++rb) {
                    accH[rb][cb] = __builtin_amdgcn_mfma_f32_16x16x32_f16(
                        af[rb], b0H[cb], accH[rb][cb], 0, 0, 0);
                    accL[rb][cb] = __builtin_amdgcn_mfma_f32_16x16x32_f16(
                        af[rb], b0L[cb], accL[rb][cb], 0, 0, 0);
                }
        }
        // load step ks+2 into set0
        if (ks + 2 < nk) {
            const int k2 = (ks + 2) * 32;
#pragma unroll
            for (int cb = 0; cb < 4; ++cb) {
                b0H[cb] = *reinterpret_cast<const f16x8*>(bptr + cb * 16 * K + k2);
                b0L[cb] = *reinterpret_cast<const f16x8*>(bptr + NK + cb * 16 * K + k2);
            }
#pragma unroll
            for (int rb = 0; rb < 4; ++rb) a0[rb] = aptr[rb][(ks + 2) * 4];
        }
        // compute step ks+1 from set1
        {
            f16x8 af[4];
#pragma unroll
            for (int rb = 0; rb < 4; ++rb) {
                unsigned int b = a1[rb];
                f16x4 lo = *reinterpret_cast<const f16x4*>(&lut4[(b & 15u) * 4]);
                f16x4 hi = *reinterpret_cast<const f16x4*>(&lut4[((b >> 4) & 15u) * 4]);
                af[rb] = __builtin_shufflevector(lo, hi, 0, 1, 2, 3, 4, 5, 6, 7);
            }
#pragma unroll
            for (int cb = 0; cb < 4; ++cb)
#pragma unroll
                for (int rb = 0; rb < 4; ++rb) {
                    accH[rb][cb] = __builtin_amdgcn_mfma_f32_16x16x32_f16(
                        af[rb], b1H[cb], accH[rb][cb], 0, 0, 0);
                    accL[rb][cb] = __builtin_amdgcn_mfma_f32_16x16x32_f16(
                        af[rb], b1L[cb], accL[rb][cb], 0, 0, 0);
                }
        }
    }

#pragma unroll
    for (int cb = 0; cb < 4; ++cb) {
        int col = n0 + wc * 64 + cb * 16 + lr;
        float bv = bias[col];
#pragma unroll
        for (int rb = 0; rb < 4; ++rb) {
            int row = m0 + wr * 64 + rb * 16 + lk * 4;
#pragma unroll
            for (int j = 0; j < 4; ++j)
                C[(size_t)(row + j) * N + col] =
                    fmaf(accL[rb][cb][j], LO_INV, accH[rb][cb][j]) + bv;
        }
    }
}

// LIF scan layer 1: thread-per-neuron; T=250 as 25 groups of 10,
// software-pipelined (next group's 10 loads issued before processing current).
__global__ __launch_bounds__(256) void scan1(
    const float* __restrict__ cur,            // [TC][131072]
    unsigned long long* __restrict__ spkb,    // [TC][2048]
    float* __restrict__ mem_c, float* __restrict__ sum_c,
    unsigned int* __restrict__ cnt_g,
    int first)
{
    int tid = blockIdx.x * 256 + threadIdx.x;  // 131072 threads
    float mem = first ? 0.f : mem_c[tid];
    float sum = first ? 0.f : sum_c[tid];
    float s = (!first && mem > 1.f) ? 1.f : 0.f;
    int cnt = 0;
    const float beta = 0.8187307530779818f;    // exp(-1/5)
    const int lane = threadIdx.x & 63;
    const int grp = tid >> 6;
    const float* base = cur + tid;

    float c[10], n[10];
#pragma unroll
    for (int i = 0; i < 10; ++i) c[i] = base[(size_t)i * 131072];

#pragma unroll
    for (int g = 0; g < 25; ++g) {
        if (g < 24) {
#pragma unroll
            for (int i = 0; i < 10; ++i)
                n[i] = base[(size_t)((g + 1) * 10 + i) * 131072];
        }
#pragma unroll
        for (int i = 0; i < 10; ++i) {
            mem = beta * mem + c[i] - s;
            bool b = mem > 1.f;
            s = b ? 1.f : 0.f;
            cnt += (int)b;
            unsigned long long B = __ballot(b);
            if (lane == 0) spkb[(size_t)(g * 10 + i) * 2048 + grp] = B;
        }
#pragma unroll
        for (int i = 0; i < 10; ++i) c[i] = n[i];
    }
    mem_c[tid] = mem;
    sum_c[tid] = sum + (float)cnt;
    int rc = cnt;
#pragma unroll
    for (int off = 32; off > 0; off >>= 1) rc += __shfl_down(rc, off);
    if (lane == 0) atomicAdd(cnt_g, (unsigned int)rc);
}

// LIF scan layer 2: same pipelined structure; accumulates mem-sum + count.
__global__ __launch_bounds__(256) void scan2(
    const float* __restrict__ cur,             // [TC][65536]
    float* __restrict__ mem_c, float* __restrict__ msum_c,
    unsigned int* __restrict__ cnt_g,
    int first)
{
    int tid = blockIdx.x * 256 + threadIdx.x;  // 65536 threads
    float mem  = first ? 0.f : mem_c[tid];
    float msum = first ? 0.f : msum_c[tid];
    float s = (!first && mem > 1.f) ? 1.f : 0.f;
    int cnt = 0;
    const float beta = 0.9048374180359595f;    // exp(-1/10)
    const float* base = cur + tid;

    float c[10], n[10];
#pragma unroll
    for (int i = 0; i < 10; ++i) c[i] = base[(size_t)i * 65536];

#pragma unroll
    for (int g = 0; g < 25; ++g) {
        if (g < 24) {
#pragma unroll
            for (int i = 0; i < 10; ++i)
                n[i] = base[(size_t)((g + 1) * 10 + i) * 65536];
        }
#pragma unroll
        for (int i = 0; i < 10; ++i) {
            mem = beta * mem + c[i] - s;
            msum += mem;
            bool b = mem > 1.f;
            s = b ? 1.f : 0.f;
            cnt += (int)b;
        }
#pragma unroll
        for (int i = 0; i < 10; ++i) c[i] = n[i];
    }
    mem_c[tid] = mem;
    msum_c[tid] = msum;
    int rc = cnt;
#pragma unroll
    for (int off = 32; off > 0; off >>= 1) rc += __shfl_down(rc, off);
    if ((threadIdx.x & 63) == 0) atomicAdd(cnt_g, (unsigned int)rc);
}

// out[b,o] = (msum[b,:]/T)@Wr[o,:] + br[o] + (s1sum[b,:]/T)@Ws[o,:] + bs[o]
__global__ __launch_bounds__(256) void readout(
    const float* __restrict__ msum, const float* __restrict__ s1sum,
    const float* __restrict__ Wr, const float* __restrict__ br,
    const float* __restrict__ Ws, const float* __restrict__ bs,
    const unsigned int* __restrict__ cnt1, const unsigned int* __restrict__ cnt2,
    float* __restrict__ out)
{
    __shared__ float r0[256], r1[256];
    int b = blockIdx.x, t = threadIdx.x;
    const float inv_t = 1.0f / 500.0f;
    float m  = msum[b * 256 + t] * inv_t;
    float p0 = m * Wr[t];
    float p1 = m * Wr[256 + t];
    float sa = s1sum[b * 512 + t] * inv_t;
    float sb = s1sum[b * 512 + 256 + t] * inv_t;
    p0 += sa * Ws[t]       + sb * Ws[256 + t];
    p1 += sa * Ws[512 + t] + sb * Ws[768 + t];
    r0[t] = p0; r1[t] = p1;
    __syncthreads();
    for (int st = 128; st > 0; st >>= 1) {
        if (t < st) { r0[t] += r0[t + st]; r1[t] += r1[t + st]; }
        __syncthreads();
    }
    if (t == 0) {
        out[b * 2 + 0] = r0[0] + br[0] + bs[0];
        out[b * 2 + 1] = r1[0] + br[1] + bs[1];
        if (b == 0) {
            out[512] = (float)cnt1[0] * (1.0f / 65536000.0f);
            out[513] = (float)cnt2[0] * (1.0f / 32768000.0f);
        }
    }
}

extern "C" void kernel_launch(void* const* d_in, const int* in_sizes, int n_in,
                              void* d_out, int out_size, void* d_ws, size_t ws_size,
                              hipStream_t stream) {
    const float* spikes = (const float*)d_in[0];
    const float* W1 = (const float*)d_in[1];
    const float* b1 = (const float*)d_in[2];
    const float* W2 = (const float*)d_in[3];
    const float* b2 = (const float*)d_in[4];
    const float* Wr = (const float*)d_in[5];
    const float* br = (const float*)d_in[6];
    const float* Ws = (const float*)d_in[7];
    const float* bs = (const float*)d_in[8];
    float* out = (float*)d_out;

    char* wsb = (char*)d_ws;
    size_t o = 0;
    unsigned short* w1s = (unsigned short*)(wsb + o); o += (size_t)2 * 65536 * 2;     // 256 KB
    unsigned short* w2s = (unsigned short*)(wsb + o); o += (size_t)2 * 131072 * 2;    // 512 KB
    unsigned long long* spbits = (unsigned long long*)(wsb + o); o += (size_t)256000 * 8; // 2 MB
    float* cur1 = (float*)(wsb + o);                  o += (size_t)TC * 131072 * 4;   // 131 MB
    float* cur2 = (float*)(wsb + o);                  o += (size_t)TC * 65536 * 4;    // 65.5 MB
    unsigned long long* spkb = (unsigned long long*)(wsb + o); o += (size_t)TC * 2048 * 8; // 4.1 MB
    float* mem1  = (float*)(wsb + o); o += 524288;
    float* s1sum = (float*)(wsb + o); o += 524288;
    float* mem2  = (float*)(wsb + o); o += 262144;
    float* msum  = (float*)(wsb + o); o += 262144;
    unsigned int* cnt1 = (unsigned int*)(wsb + o); o += 256;
    unsigned int* cnt2 = (unsigned int*)(wsb + o); o += 256;

    prep_weights<<<512, 256, 0, stream>>>(W1, W2, w1s, w2s, cnt1, cnt2);
    pack_spikes<<<64000, 256, 0, stream>>>(spikes, spbits);

    const int M = TC * BATCH;   // 64000 rows per chunk
    for (int c = 0; c < NCHUNK; ++c) {
        const unsigned char* Ac = (const unsigned char*)spbits + (size_t)c * M * (NIN / 8);
        gemm_bits<NH1, NIN><<<dim3(M / 128, NH1 / 128), 256, 0, stream>>>(
            Ac, w1s, b1, cur1, M);
        scan1<<<512, 256, 0, stream>>>(cur1, spkb, mem1, s1sum, cnt1, c == 0);
        gemm_bits<NH2, NH1><<<dim3(M / 128, NH2 / 128), 256, 0, stream>>>(
            (const unsigned char*)spkb, w2s, b2, cur2, M);
        scan2<<<256, 256, 0, stream>>>(cur2, mem2, msum, cnt2, c == 0);
    }

    readout<<<256, 256, 0, stream>>>(msum, s1sum, Wr, br, Ws, bs, cnt1, cnt2, out);
}

// Round 12
// 331.506 us; speedup vs baseline: 1.4205x; 1.4205x over previous
//
#include <hip/hip_runtime.h>
#include <hip/hip_bf16.h>
#include <hip/hip_fp16.h>

typedef __attribute__((ext_vector_type(8))) short short8;
typedef __attribute__((ext_vector_type(4))) short short4v;
typedef __attribute__((ext_vector_type(8))) _Float16 f16x8;
typedef __attribute__((ext_vector_type(4))) _Float16 f16x4;
typedef __attribute__((ext_vector_type(4))) float f32x4;

static constexpr int BATCH   = 256;
static constexpr int NIN     = 128;
static constexpr int NH1     = 512;
static constexpr int NH2     = 256;
static constexpr int TC      = 250;   // chunk length (2 chunks of 250)
static constexpr int NCHUNK  = 2;
static constexpr float LO_SCALE = 4096.0f;        // 2^12
static constexpr float LO_INV   = 2.44140625e-4f; // 2^-12

__device__ __forceinline__ unsigned short f2h_bits(float x) {
    _Float16 h = (_Float16)x;
    unsigned short u;
    __builtin_memcpy(&u, &h, 2);
    return u;
}
__device__ __forceinline__ float h2f(unsigned short u) {
    _Float16 h;
    __builtin_memcpy(&h, &u, 2);
    return (float)h;
}

__device__ __forceinline__ void gload16(const unsigned short* g, unsigned short* l) {
    __builtin_amdgcn_global_load_lds(
        (const __attribute__((address_space(1))) unsigned int*)(g),
        (__attribute__((address_space(3))) unsigned int*)(l),
        16, 0, 0);
}

// Split f32 weights into 2 f16 components: w = hi + lo*2^-12 (residual ~|w|*2^-23).
// Also zeroes the two atomic spike counters (deterministic each launch).
__global__ __launch_bounds__(256) void prep_weights(
    const float* __restrict__ W1, const float* __restrict__ W2,
    unsigned short* __restrict__ w1s,   // [2][512*128] f16 bits
    unsigned short* __restrict__ w2s,   // [2][256*512]
    unsigned int* __restrict__ cnt1, unsigned int* __restrict__ cnt2)
{
    int idx = blockIdx.x * 256 + threadIdx.x;
    if (idx == 0) { cnt1[0] = 0u; cnt2[0] = 0u; }
    const int n1 = NH1 * NIN;   // 65536
    const int n2 = NH2 * NH1;   // 131072
    if (idx < n1) {
        float w = W1[idx];
        unsigned short hi = f2h_bits(w);
        float r = (w - h2f(hi)) * LO_SCALE;
        unsigned short lo = f2h_bits(r);
        w1s[idx] = hi; w1s[n1 + idx] = lo;
    }
    if (idx < n2) {
        float w = W2[idx];
        unsigned short hi = f2h_bits(w);
        float r = (w - h2f(hi)) * LO_SCALE;
        unsigned short lo = f2h_bits(r);
        w2s[idx] = hi; w2s[n2 + idx] = lo;
    }
}

// Pack f32 spikes (exact 0/1) into bits, element order preserved.
__global__ __launch_bounds__(256) void pack_spikes(
    const float* __restrict__ sp, unsigned long long* __restrict__ bits)
{
    int i = blockIdx.x * 256 + threadIdx.x;   // 16,384,000 threads
    bool b = sp[i] != 0.0f;
    unsigned long long m = __ballot(b);
    if ((threadIdx.x & 63) == 0) bits[i >> 6] = m;
}

// Unified bit-A GEMM: C[M,N] = bits(A)[M,K] * (Bhi + 2^-12*Blo)[N,K]^T + bias
// BM=128 BN=128 BK=32; 4 waves 2x2, wave tile 64x64, dual f32 acc.
// A: bit-packed; conflict-free nibble LUT (16 x 8B = 1:1 banks; broadcast).
// B: global_load_lds w16, source-swizzled (rule #21), TRI-BUFFERED with a
//    SINGLE barrier per K-step:
//      iter j: vmcnt(8)[G(j),A(j) landed; G(j+1) in flight] -> s_barrier
//              -> stage G(j+2) into buf (j+2)%3 (its readers, compute(j-1),
//                 all finished before the barrier) -> compute(j).
//    2 steps in flight across every barrier; half the barriers of R10.
template<int N, int K>
__global__ __launch_bounds__(256) void gemm_bits(
    const unsigned char* __restrict__ Ab,    // [M][K/8]
    const unsigned short* __restrict__ Bs,   // [2][N*K] f16 bits
    const float* __restrict__ bias,
    float* __restrict__ C,
    int M)
{
    constexpr int NK = N * K;
    constexpr int nk = K / 32;
    constexpr int kb = K / 8;

    __shared__ __align__(16) unsigned short Bsh[3][8192];   // 48 KB (3 x 16KB)
    __shared__ __align__(16) unsigned short lut4[64];       // 128 B: 16 x 4 f16

    const int tid  = threadIdx.x;
    const int w    = tid >> 6;
    const int lane = tid & 63;
    const int lr   = lane & 15;
    const int lk   = lane >> 4;
    const int wr   = w >> 1;
    const int wc   = w & 1;

    // nibble LUT: entry n = 4 f16 (bit i of n -> 1.0/0.0)
    if (tid < 16) {
        short4v e;
#pragma unroll
        for (int i = 0; i < 4; ++i)
            e[i] = ((tid >> i) & 1) ? (short)0x3C00 : (short)0;
        *reinterpret_cast<short4v*>(&lut4[tid * 4]) = e;
    }
    asm volatile("s_waitcnt lgkmcnt(0)" ::: "memory");  // LUT writes retired;
    // published to other waves by the iter-0 s_barrier below.

    const int m0 = blockIdx.x * 128;
    const int n0 = blockIdx.y * 128;
    const int ulog = ((lane & 3) ^ ((lane >> 3) & 3)) * 8;

    int gBoff[4], lBoff[4];
#pragma unroll
    for (int j = 0; j < 4; ++j) {
        int i = w * 4 + j;
        int s = i >> 3, blk = i & 7;
        int row = blk * 16 + (lane >> 2);
        gBoff[j] = s * NK + (n0 + row) * K + ulog;
        lBoff[j] = s * 4096 + blk * 512;
    }
    const unsigned char* aptr[4];
#pragma unroll
    for (int rb = 0; rb < 4; ++rb)
        aptr[rb] = Ab + (size_t)(m0 + wr * 64 + rb * 16 + lr) * kb + lk;

    f32x4 accH[4][4], accL[4][4];
#pragma unroll
    for (int i = 0; i < 4; ++i)
#pragma unroll
        for (int j = 0; j < 4; ++j) {
            accH[i][j] = (f32x4){0.f, 0.f, 0.f, 0.f};
            accL[i][j] = (f32x4){0.f, 0.f, 0.f, 0.f};
        }

    unsigned int ab[3][4];
    // prologue: stage K-steps 0 and 1 (16 vmem ops outstanding: G0,A0,G1,A1)
#pragma unroll
    for (int p = 0; p < 2; ++p) {
#pragma unroll
        for (int j = 0; j < 4; ++j)
            gload16(Bs + gBoff[j] + p * 32, &Bsh[p][lBoff[j]]);
#pragma unroll
        for (int rb = 0; rb < 4; ++rb)
            ab[p][rb] = aptr[rb][p * 4];
    }

#pragma unroll
    for (int ks = 0; ks < nk; ++ks) {
        // wait: G(ks),A(ks) landed; G(ks+1),A(ks+1) (8 ops) stay in flight
        if (ks + 1 < nk) {
            asm volatile("s_waitcnt vmcnt(8)" ::: "memory");
        } else {
            asm volatile("s_waitcnt vmcnt(0)" ::: "memory");
        }
        __builtin_amdgcn_s_barrier();
        __builtin_amdgcn_sched_barrier(0);

        // stage ks+2 into buf (ks+2)%3 == (ks-1)%3 (readers done pre-barrier)
        if (ks + 2 < nk) {
#pragma unroll
            for (int j = 0; j < 4; ++j)
                gload16(Bs + gBoff[j] + (ks + 2) * 32, &Bsh[(ks + 2) % 3][lBoff[j]]);
#pragma unroll
            for (int rb = 0; rb < 4; ++rb)
                ab[(ks + 2) % 3][rb] = aptr[rb][(ks + 2) * 4];
        }
        __builtin_amdgcn_sched_barrier(0);   // keep stage cluster here (vmcnt math)

        f16x8 af[4];
#pragma unroll
        for (int rb = 0; rb < 4; ++rb) {
            unsigned int b = ab[ks % 3][rb];
            f16x4 lo = *reinterpret_cast<const f16x4*>(&lut4[(b & 15u) * 4]);
            f16x4 hi = *reinterpret_cast<const f16x4*>(&lut4[((b >> 4) & 15u) * 4]);
            af[rb] = __builtin_shufflevector(lo, hi, 0, 1, 2, 3, 4, 5, 6, 7);
        }

#pragma unroll
        for (int cb = 0; cb < 4; ++cb) {
            int row = wc * 64 + cb * 16 + lr;
            int u = (lk ^ ((row >> 1) & 3)) * 8;
            f16x8 bfH = *reinterpret_cast<const f16x8*>(&Bsh[ks % 3][row * 32 + u]);
            f16x8 bfL = *reinterpret_cast<const f16x8*>(&Bsh[ks % 3][4096 + row * 32 + u]);
#pragma unroll
            for (int rb = 0; rb < 4; ++rb) {
                accH[rb][cb] = __builtin_amdgcn_mfma_f32_16x16x32_f16(
                    af[rb], bfH, accH[rb][cb], 0, 0, 0);
                accL[rb][cb] = __builtin_amdgcn_mfma_f32_16x16x32_f16(
                    af[rb], bfL, accL[rb][cb], 0, 0, 0);
            }
        }
    }

#pragma unroll
    for (int cb = 0; cb < 4; ++cb) {
        int col = n0 + wc * 64 + cb * 16 + lr;
        float bv = bias[col];
#pragma unroll
        for (int rb = 0; rb < 4; ++rb) {
            int row = m0 + wr * 64 + rb * 16 + lk * 4;
#pragma unroll
            for (int j = 0; j < 4; ++j)
                C[(size_t)(row + j) * N + col] =
                    fmaf(accL[rb][cb][j], LO_INV, accH[rb][cb][j]) + bv;
        }
    }
}

// LIF scan layer 1: thread-per-neuron; T=250 as 25 groups of 10,
// software-pipelined (next group's 10 loads issued before processing current).
__global__ __launch_bounds__(256) void scan1(
    const float* __restrict__ cur,            // [TC][131072]
    unsigned long long* __restrict__ spkb,    // [TC][2048]
    float* __restrict__ mem_c, float* __restrict__ sum_c,
    unsigned int* __restrict__ cnt_g,
    int first)
{
    int tid = blockIdx.x * 256 + threadIdx.x;  // 131072 threads
    float mem = first ? 0.f : mem_c[tid];
    float sum = first ? 0.f : sum_c[tid];
    float s = (!first && mem > 1.f) ? 1.f : 0.f;
    int cnt = 0;
    const float beta = 0.8187307530779818f;    // exp(-1/5)
    const int lane = threadIdx.x & 63;
    const int grp = tid >> 6;
    const float* base = cur + tid;

    float c[10], n[10];
#pragma unroll
    for (int i = 0; i < 10; ++i) c[i] = base[(size_t)i * 131072];

#pragma unroll
    for (int g = 0; g < 25; ++g) {
        if (g < 24) {
#pragma unroll
            for (int i = 0; i < 10; ++i)
                n[i] = base[(size_t)((g + 1) * 10 + i) * 131072];
        }
#pragma unroll
        for (int i = 0; i < 10; ++i) {
            mem = beta * mem + c[i] - s;
            bool b = mem > 1.f;
            s = b ? 1.f : 0.f;
            cnt += (int)b;
            unsigned long long B = __ballot(b);
            if (lane == 0) spkb[(size_t)(g * 10 + i) * 2048 + grp] = B;
        }
#pragma unroll
        for (int i = 0; i < 10; ++i) c[i] = n[i];
    }
    mem_c[tid] = mem;
    sum_c[tid] = sum + (float)cnt;
    int rc = cnt;
#pragma unroll
    for (int off = 32; off > 0; off >>= 1) rc += __shfl_down(rc, off);
    if (lane == 0) atomicAdd(cnt_g, (unsigned int)rc);
}

// LIF scan layer 2: same pipelined structure; accumulates mem-sum + count.
__global__ __launch_bounds__(256) void scan2(
    const float* __restrict__ cur,             // [TC][65536]
    float* __restrict__ mem_c, float* __restrict__ msum_c,
    unsigned int* __restrict__ cnt_g,
    int first)
{
    int tid = blockIdx.x * 256 + threadIdx.x;  // 65536 threads
    float mem  = first ? 0.f : mem_c[tid];
    float msum = first ? 0.f : msum_c[tid];
    float s = (!first && mem > 1.f) ? 1.f : 0.f;
    int cnt = 0;
    const float beta = 0.9048374180359595f;    // exp(-1/10)
    const float* base = cur + tid;

    float c[10], n[10];
#pragma unroll
    for (int i = 0; i < 10; ++i) c[i] = base[(size_t)i * 65536];

#pragma unroll
    for (int g = 0; g < 25; ++g) {
        if (g < 24) {
#pragma unroll
            for (int i = 0; i < 10; ++i)
                n[i] = base[(size_t)((g + 1) * 10 + i) * 65536];
        }
#pragma unroll
        for (int i = 0; i < 10; ++i) {
            mem = beta * mem + c[i] - s;
            msum += mem;
            bool b = mem > 1.f;
            s = b ? 1.f : 0.f;
            cnt += (int)b;
        }
#pragma unroll
        for (int i = 0; i < 10; ++i) c[i] = n[i];
    }
    mem_c[tid] = mem;
    msum_c[tid] = msum;
    int rc = cnt;
#pragma unroll
    for (int off = 32; off > 0; off >>= 1) rc += __shfl_down(rc, off);
    if ((threadIdx.x & 63) == 0) atomicAdd(cnt_g, (unsigned int)rc);
}

// out[b,o] = (msum[b,:]/T)@Wr[o,:] + br[o] + (s1sum[b,:]/T)@Ws[o,:] + bs[o]
__global__ __launch_bounds__(256) void readout(
    const float* __restrict__ msum, const float* __restrict__ s1sum,
    const float* __restrict__ Wr, const float* __restrict__ br,
    const float* __restrict__ Ws, const float* __restrict__ bs,
    const unsigned int* __restrict__ cnt1, const unsigned int* __restrict__ cnt2,
    float* __restrict__ out)
{
    __shared__ float r0[256], r1[256];
    int b = blockIdx.x, t = threadIdx.x;
    const float inv_t = 1.0f / 500.0f;
    float m  = msum[b * 256 + t] * inv_t;
    float p0 = m * Wr[t];
    float p1 = m * Wr[256 + t];
    float sa = s1sum[b * 512 + t] * inv_t;
    float sb = s1sum[b * 512 + 256 + t] * inv_t;
    p0 += sa * Ws[t]       + sb * Ws[256 + t];
    p1 += sa * Ws[512 + t] + sb * Ws[768 + t];
    r0[t] = p0; r1[t] = p1;
    __syncthreads();
    for (int st = 128; st > 0; st >>= 1) {
        if (t < st) { r0[t] += r0[t + st]; r1[t] += r1[t + st]; }
        __syncthreads();
    }
    if (t == 0) {
        out[b * 2 + 0] = r0[0] + br[0] + bs[0];
        out[b * 2 + 1] = r1[0] + br[1] + bs[1];
        if (b == 0) {
            out[512] = (float)cnt1[0] * (1.0f / 65536000.0f);
            out[513] = (float)cnt2[0] * (1.0f / 32768000.0f);
        }
    }
}

extern "C" void kernel_launch(void* const* d_in, const int* in_sizes, int n_in,
                              void* d_out, int out_size, void* d_ws, size_t ws_size,
                              hipStream_t stream) {
    const float* spikes = (const float*)d_in[0];
    const float* W1 = (const float*)d_in[1];
    const float* b1 = (const float*)d_in[2];
    const float* W2 = (const float*)d_in[3];
    const float* b2 = (const float*)d_in[4];
    const float* Wr = (const float*)d_in[5];
    const float* br = (const float*)d_in[6];
    const float* Ws = (const float*)d_in[7];
    const float* bs = (const float*)d_in[8];
    float* out = (float*)d_out;

    char* wsb = (char*)d_ws;
    size_t o = 0;
    unsigned short* w1s = (unsigned short*)(wsb + o); o += (size_t)2 * 65536 * 2;     // 256 KB
    unsigned short* w2s = (unsigned short*)(wsb + o); o += (size_t)2 * 131072 * 2;    // 512 KB
    unsigned long long* spbits = (unsigned long long*)(wsb + o); o += (size_t)256000 * 8; // 2 MB
    float* cur1 = (float*)(wsb + o);                  o += (size_t)TC * 131072 * 4;   // 131 MB
    float* cur2 = (float*)(wsb + o);                  o += (size_t)TC * 65536 * 4;    // 65.5 MB
    unsigned long long* spkb = (unsigned long long*)(wsb + o); o += (size_t)TC * 2048 * 8; // 4.1 MB
    float* mem1  = (float*)(wsb + o); o += 524288;
    float* s1sum = (float*)(wsb + o); o += 524288;
    float* mem2  = (float*)(wsb + o); o += 262144;
    float* msum  = (float*)(wsb + o); o += 262144;
    unsigned int* cnt1 = (unsigned int*)(wsb + o); o += 256;
    unsigned int* cnt2 = (unsigned int*)(wsb + o); o += 256;

    prep_weights<<<512, 256, 0, stream>>>(W1, W2, w1s, w2s, cnt1, cnt2);
    pack_spikes<<<64000, 256, 0, stream>>>(spikes, spbits);

    const int M = TC * BATCH;   // 64000 rows per chunk
    for (int c = 0; c < NCHUNK; ++c) {
        const unsigned char* Ac = (const unsigned char*)spbits + (size_t)c * M * (NIN / 8);
        gemm_bits<NH1, NIN><<<dim3(M / 128, NH1 / 128), 256, 0, stream>>>(
            Ac, w1s, b1, cur1, M);
        scan1<<<512, 256, 0, stream>>>(cur1, spkb, mem1, s1sum, cnt1, c == 0);
        gemm_bits<NH2, NH1><<<dim3(M / 128, NH2 / 128), 256, 0, stream>>>(
            (const unsigned char*)spkb, w2s, b2, cur2, M);
        scan2<<<256, 256, 0, stream>>>(cur2, mem2, msum, cnt2, c == 0);
    }

    readout<<<256, 256, 0, stream>>>(msum, s1sum, Wr, br, Ws, bs, cnt1, cnt2, out);
}